// Round 1
// baseline (1127.630 us; speedup 1.0000x reference)
//
#include <hip/hip_runtime.h>
#include <hip/hip_bf16.h>

typedef unsigned short u16;
typedef __attribute__((ext_vector_type(8))) unsigned short ushort8;

// N=16, L=4096, IN_DIM=32, D=E=512
#define NB 16
#define SEQ 4096
#define DIM 512
#define INDIM 32
#define NTOK (NB * SEQ)   // 65536

static __device__ __forceinline__ u16 f2bf(float f) {
    union { float f; unsigned u; } x; x.f = f;
    unsigned r = (x.u + 0x7FFFu + ((x.u >> 16) & 1u)) >> 16;
    return (u16)r;
}
static __device__ __forceinline__ float bf2f(u16 b) {
    union { unsigned u; float f; } x; x.u = ((unsigned)b) << 16;
    return x.f;
}

// ---------------- Kernel 1a: h = x @ w_in^T + b_in  (store bf16) ----------------
__global__ __launch_bounds__(256) void k_hproj(const float* __restrict__ x,
                                               const float* __restrict__ w_in,
                                               const float* __restrict__ b_in,
                                               u16* __restrict__ hbf) {
    __shared__ float s_w[DIM * INDIM];  // 64 KiB
    __shared__ float s_b[DIM];
    int tid = threadIdx.x;
    const float4* wg = (const float4*)w_in;
    float4* ws4 = (float4*)s_w;
    #pragma unroll
    for (int i = 0; i < 16; ++i) ws4[tid + i * 256] = wg[tid + i * 256];
    if (tid < 128) ((float4*)s_b)[tid] = ((const float4*)b_in)[tid];
    __syncthreads();

    long token = (long)blockIdx.x * 256 + tid;  // 256 blocks -> 65536 tokens
    const float4* xr = (const float4*)(x + token * INDIM);
    float xv[32];
    #pragma unroll
    for (int i = 0; i < 8; ++i) {
        float4 t = xr[i];
        xv[4*i] = t.x; xv[4*i+1] = t.y; xv[4*i+2] = t.z; xv[4*i+3] = t.w;
    }
    for (int d0 = 0; d0 < DIM; d0 += 8) {
        u16 ob[8];
        #pragma unroll
        for (int dd = 0; dd < 8; ++dd) {
            int d = d0 + dd;
            float acc = s_b[d];
            const float* wr = s_w + d * INDIM;
            #pragma unroll
            for (int j = 0; j < 32; ++j) acc += xv[j] * wr[j];
            ob[dd] = f2bf(acc);
        }
        *((ushort8*)(hbf + token * DIM + d0)) = *((ushort8*)ob);
    }
}

// ------- Kernel 1b: Kf = elu(h @ wk^T + bk)+1 (bf16) + per-batch Ksum atomics -------
// NT GEMM: M=65536 tokens (h rows, bf16), N=512 (wk rows, f32), K=512.
__global__ __launch_bounds__(256) void k_kproj(const u16* __restrict__ hbf,
                                               const float* __restrict__ wk,
                                               const float* __restrict__ bk,
                                               u16* __restrict__ kf,
                                               float* __restrict__ ksum) {
    __shared__ float sA[32 * 128];  // [k][token]
    __shared__ float sB[32 * 128];  // [k][e]
    int tid = threadIdx.x;
    int tM = blockIdx.x;            // 0..511  (token tiles of 128)
    int tN = blockIdx.y;            // 0..3    (e tiles of 128)
    int tx = tid & 15, ty = tid >> 4;
    int t_base = tM * 128;
    int e_base = tN * 128;
    float acc[8][8] = {};

    for (int k0 = 0; k0 < DIM; k0 += 32) {
        // stage A (transpose into [k][t])
        {
            int c0 = tid * 2;
            #pragma unroll
            for (int l = 0; l < 2; ++l) {
                int c = c0 + l;            // 0..511
                int t = c >> 2;            // 0..127
                int doff = (c & 3) * 8;    // 0,8,16,24
                ushort8 hv = *((const ushort8*)(hbf + (long)(t_base + t) * DIM + k0 + doff));
                #pragma unroll
                for (int j = 0; j < 8; ++j)
                    sA[(doff + j) * 128 + t] = bf2f(((u16*)&hv)[j]);
            }
        }
        // stage B (transpose into [k][e])
        {
            int c0 = tid * 4;
            #pragma unroll
            for (int l = 0; l < 4; ++l) {
                int c = c0 + l;            // 0..1023
                int e = c >> 3;            // 0..127
                int doff = (c & 7) * 4;    // 0..28
                float4 wv = *((const float4*)(wk + (long)(e_base + e) * DIM + k0 + doff));
                sB[(doff + 0) * 128 + e] = wv.x;
                sB[(doff + 1) * 128 + e] = wv.y;
                sB[(doff + 2) * 128 + e] = wv.z;
                sB[(doff + 3) * 128 + e] = wv.w;
            }
        }
        __syncthreads();
        #pragma unroll
        for (int kk = 0; kk < 32; ++kk) {
            float a[8], b[8];
            #pragma unroll
            for (int i = 0; i < 8; ++i) a[i] = sA[kk * 128 + ty * 8 + i];
            #pragma unroll
            for (int i = 0; i < 8; ++i) b[i] = sB[kk * 128 + tx * 8 + i];
            #pragma unroll
            for (int r = 0; r < 8; ++r)
                #pragma unroll
                for (int c = 0; c < 8; ++c) acc[r][c] += a[r] * b[c];
        }
        __syncthreads();
    }

    // epilogue: bias + (elu+1), store bf16, accumulate column sums
    float bkv[8];
    #pragma unroll
    for (int c = 0; c < 8; ++c) bkv[c] = bk[e_base + tx * 8 + c];
    float colsum[8] = {};
    #pragma unroll
    for (int r = 0; r < 8; ++r) {
        u16 ob[8];
        #pragma unroll
        for (int c = 0; c < 8; ++c) {
            float v = acc[r][c] + bkv[c];
            v = (v > 0.f) ? (v + 1.f) : expf(v);  // elu(v)+1
            colsum[c] += v;
            ob[c] = f2bf(v);
        }
        *((ushort8*)(kf + (long)(t_base + ty * 8 + r) * DIM + e_base + tx * 8)) = *((ushort8*)ob);
    }
    // reduce colsum across ty (16 rows of threads) via LDS, then one atomic/column
    #pragma unroll
    for (int c = 0; c < 8; ++c) sA[ty * 128 + tx * 8 + c] = colsum[c];
    __syncthreads();
    if (tid < 128) {
        float s = 0.f;
        #pragma unroll
        for (int r = 0; r < 16; ++r) s += sA[r * 128 + tid];
        int batch = t_base >> 12;  // 4096 tokens per batch
        atomicAdd(&ksum[batch * DIM + e_base + tid], s);
    }
}

// ---------- Kernel 2: A[n] = Kf[n]^T @ h[n]   (TN GEMM, K=4096, per batch) ----------
__global__ __launch_bounds__(256) void k_kv(const u16* __restrict__ kf,
                                            const u16* __restrict__ hbf,
                                            float* __restrict__ Aout) {
    __shared__ float sA[32 * 128];  // [s][d]
    __shared__ float sB[32 * 128];  // [s][m]
    int tid = threadIdx.x;
    int b = blockIdx.y;
    int tM = blockIdx.x >> 2;   // d tile 0..3
    int tN = blockIdx.x & 3;    // m tile 0..3
    int tx = tid & 15, ty = tid >> 4;
    int d_base = tM * 128, m_base = tN * 128;
    long s_base = (long)b * SEQ;
    float acc[8][8] = {};

    int sr = tid >> 3;            // 0..31
    int coff = (tid & 7) * 16;    // 0..112
    for (int k0 = 0; k0 < SEQ; k0 += 32) {
        {
            const u16* src = kf + (s_base + k0 + sr) * DIM + d_base + coff;
            ushort8 v0 = *((const ushort8*)src);
            ushort8 v1 = *((const ushort8*)(src + 8));
            float* dst = sA + sr * 128 + coff;
            #pragma unroll
            for (int j = 0; j < 8; ++j) dst[j] = bf2f(((u16*)&v0)[j]);
            #pragma unroll
            for (int j = 0; j < 8; ++j) dst[8 + j] = bf2f(((u16*)&v1)[j]);
        }
        {
            const u16* src = hbf + (s_base + k0 + sr) * DIM + m_base + coff;
            ushort8 v0 = *((const ushort8*)src);
            ushort8 v1 = *((const ushort8*)(src + 8));
            float* dst = sB + sr * 128 + coff;
            #pragma unroll
            for (int j = 0; j < 8; ++j) dst[j] = bf2f(((u16*)&v0)[j]);
            #pragma unroll
            for (int j = 0; j < 8; ++j) dst[8 + j] = bf2f(((u16*)&v1)[j]);
        }
        __syncthreads();
        #pragma unroll
        for (int kk = 0; kk < 32; ++kk) {
            float a[8], bb[8];
            #pragma unroll
            for (int i = 0; i < 8; ++i) a[i] = sA[kk * 128 + ty * 8 + i];
            #pragma unroll
            for (int i = 0; i < 8; ++i) bb[i] = sB[kk * 128 + tx * 8 + i];
            #pragma unroll
            for (int r = 0; r < 8; ++r)
                #pragma unroll
                for (int c = 0; c < 8; ++c) acc[r][c] += a[r] * bb[c];
        }
        __syncthreads();
    }
    #pragma unroll
    for (int r = 0; r < 8; ++r) {
        float4 v0 = { acc[r][0], acc[r][1], acc[r][2], acc[r][3] };
        float4 v1 = { acc[r][4], acc[r][5], acc[r][6], acc[r][7] };
        float* out = Aout + ((long)b * DIM + d_base + ty * 8 + r) * DIM + m_base + tx * 8;
        *((float4*)out) = v0;
        *((float4*)(out + 4)) = v1;
    }
}

// ---------------- Kernel 3: per-batch finalize at l=0 ----------------
__device__ __forceinline__ float dot512(const float* __restrict__ w, const float* v) {
    const float4* a = (const float4*)w;
    const float4* b = (const float4*)v;
    float acc = 0.f;
    #pragma unroll 4
    for (int j = 0; j < 128; ++j) {
        float4 p = a[j], q = b[j];
        acc += p.x * q.x + p.y * q.y + p.z * q.z + p.w * q.w;
    }
    return acc;
}

__device__ __forceinline__ float block_reduce(float v, float* sred, int tid) {
    sred[tid] = v;
    __syncthreads();
    for (int s = 128; s > 0; s >>= 1) {
        if (tid < s) sred[tid] += sred[tid + s];
        __syncthreads();
    }
    float r = sred[0];
    __syncthreads();
    return r;
}

__global__ __launch_bounds__(256) void k_final(
    const float* __restrict__ x, const float* __restrict__ w_in, const float* __restrict__ b_in,
    const float* __restrict__ wq, const float* __restrict__ bq,
    const float* __restrict__ wv, const float* __restrict__ bv,
    const float* __restrict__ wo, const float* __restrict__ bo,
    const float* __restrict__ g1, const float* __restrict__ b1,
    const float* __restrict__ wff1, const float* __restrict__ bff1,
    const float* __restrict__ wff2, const float* __restrict__ bff2,
    const float* __restrict__ g2, const float* __restrict__ b2,
    const float* __restrict__ gf, const float* __restrict__ bfv,
    const float* __restrict__ wfc, const float* __restrict__ bfc,
    const float* __restrict__ Aout, const float* __restrict__ ksum,
    float* __restrict__ out) {
    __shared__ float sv[DIM];    // h0, later residual
    __shared__ float sq[DIM];    // Q0
    __shared__ float su[DIM];    // u, later o, later r1+y
    __shared__ float sr1[DIM];   // LN1 output
    __shared__ float sf[DIM];    // attn / ff / final
    __shared__ float sred[256];
    __shared__ float sx[INDIM];
    __shared__ float s_sc[2];

    int n = blockIdx.x, tid = threadIdx.x;
    if (tid < 32) sx[tid] = x[(long)n * SEQ * INDIM + tid];
    __syncthreads();

    // h0 (fp32, recomputed exactly)
    for (int d = tid; d < DIM; d += 256) {
        float acc = b_in[d];
        const float* wr = w_in + d * INDIM;
        #pragma unroll
        for (int j = 0; j < 32; ++j) acc += sx[j] * wr[j];
        sv[d] = acc;
    }
    __syncthreads();

    // Q0 = elu(wq@h0+bq)+1
    for (int e = tid; e < DIM; e += 256) {
        float acc = bq[e] + dot512(wq + (long)e * DIM, sv);
        sq[e] = (acc > 0.f) ? (acc + 1.f) : expf(acc);
    }
    __syncthreads();

    // zdot = Q0 . Ksum[n];  Z = 1/(zdot + eps)
    {
        float p = 0.f;
        for (int j = tid; j < DIM; j += 256) p += sq[j] * ksum[n * DIM + j];
        float tot = block_reduce(p, sred, tid);
        if (tid == 0) { s_sc[0] = tot; s_sc[1] = 1.f / (tot + 1e-6f); }
        __syncthreads();
    }

    // u = A[n]^T Q0  (coalesced: row-sweep over d)
    {
        float u0 = 0.f, u1 = 0.f;
        const float* An = Aout + (long)n * DIM * DIM;
        for (int d = 0; d < DIM; ++d) {
            float qd = sq[d];
            u0 += qd * An[d * DIM + tid];
            u1 += qd * An[d * DIM + tid + 256];
        }
        su[tid] = u0;
        su[tid + 256] = u1;
    }
    __syncthreads();

    // attn = Z*(wv @ u) + (zdot*Z)*bv
    {
        float Z = s_sc[1], dz = s_sc[0] * s_sc[1];
        for (int m = tid; m < DIM; m += 256)
            sf[m] = Z * dot512(wv + (long)m * DIM, su) + dz * bv[m];
    }
    __syncthreads();

    // o = wo @ attn + bo
    for (int d = tid; d < DIM; d += 256)
        su[d] = bo[d] + dot512(wo + (long)d * DIM, sf);
    __syncthreads();

    // r = h0 + o ; LN1
    {
        float p0 = 0.f, p1 = 0.f;
        for (int d = tid; d < DIM; d += 256) {
            float v = sv[d] + su[d];
            sv[d] = v;
            p0 += v; p1 += v * v;
        }
        float mu = block_reduce(p0, sred, tid) * (1.f / DIM);
        float ms = block_reduce(p1, sred, tid) * (1.f / DIM);
        float inv = rsqrtf(ms - mu * mu + 1e-5f);
        for (int d = tid; d < DIM; d += 256)
            sr1[d] = (sv[d] - mu) * inv * g1[d] + b1[d];
        __syncthreads();
    }

    // FF: f = relu(wff1@r1+bff1); y = wff2@f+bff2; r2in = r1+y
    for (int e = tid; e < DIM; e += 256) {
        float acc = bff1[e] + dot512(wff1 + (long)e * DIM, sr1);
        sf[e] = acc > 0.f ? acc : 0.f;
    }
    __syncthreads();
    for (int d = tid; d < DIM; d += 256)
        su[d] = sr1[d] + bff2[d] + dot512(wff2 + (long)d * DIM, sf);
    __syncthreads();

    // LN2
    {
        float p0 = 0.f, p1 = 0.f;
        for (int d = tid; d < DIM; d += 256) { float v = su[d]; p0 += v; p1 += v * v; }
        float mu = block_reduce(p0, sred, tid) * (1.f / DIM);
        float ms = block_reduce(p1, sred, tid) * (1.f / DIM);
        float inv = rsqrtf(ms - mu * mu + 1e-5f);
        for (int d = tid; d < DIM; d += 256)
            sv[d] = (su[d] - mu) * inv * g2[d] + b2[d];
        __syncthreads();
    }
    // LN-final
    {
        float p0 = 0.f, p1 = 0.f;
        for (int d = tid; d < DIM; d += 256) { float v = sv[d]; p0 += v; p1 += v * v; }
        float mu = block_reduce(p0, sred, tid) * (1.f / DIM);
        float ms = block_reduce(p1, sred, tid) * (1.f / DIM);
        float inv = rsqrtf(ms - mu * mu + 1e-5f);
        for (int d = tid; d < DIM; d += 256)
            sf[d] = (sv[d] - mu) * inv * gf[d] + bfv[d];
        __syncthreads();
    }
    // out[n] = w_fc . h3 + b_fc
    {
        float p = 0.f;
        for (int d = tid; d < DIM; d += 256) p += wfc[d] * sf[d];
        float tot = block_reduce(p, sred, tid);
        if (tid == 0) out[n] = tot + bfc[0];
    }
}

extern "C" void kernel_launch(void* const* d_in, const int* in_sizes, int n_in,
                              void* d_out, int out_size, void* d_ws, size_t ws_size,
                              hipStream_t stream) {
    const float* x    = (const float*)d_in[0];
    const float* w_in = (const float*)d_in[1];
    const float* b_in = (const float*)d_in[2];
    const float* wq   = (const float*)d_in[3];
    const float* bq   = (const float*)d_in[4];
    const float* wk   = (const float*)d_in[5];
    const float* bk   = (const float*)d_in[6];
    const float* wv   = (const float*)d_in[7];
    const float* bv   = (const float*)d_in[8];
    const float* wo   = (const float*)d_in[9];
    const float* bo   = (const float*)d_in[10];
    const float* g1   = (const float*)d_in[11];
    const float* b1   = (const float*)d_in[12];
    const float* wff1 = (const float*)d_in[13];
    const float* bff1 = (const float*)d_in[14];
    const float* wff2 = (const float*)d_in[15];
    const float* bff2 = (const float*)d_in[16];
    const float* g2   = (const float*)d_in[17];
    const float* b2   = (const float*)d_in[18];
    const float* gf   = (const float*)d_in[19];
    const float* bf   = (const float*)d_in[20];
    const float* wfc  = (const float*)d_in[21];
    const float* bfc  = (const float*)d_in[22];

    char* ws = (char*)d_ws;
    u16*   hbf  = (u16*)ws;                         // 64 MiB : h bf16 [65536][512]
    u16*   kf   = (u16*)(ws + (64ull << 20));       // 64 MiB : Kf bf16 [65536][512]
    float* Aout = (float*)(ws + (128ull << 20));    // 16 MiB : A fp32 [16][512][512]
    float* ksum = (float*)(ws + (144ull << 20));    // 32 KiB : Ksum fp32 [16][512]

    hipMemsetAsync(ksum, 0, NB * DIM * sizeof(float), stream);
    k_hproj<<<256, 256, 0, stream>>>(x, w_in, b_in, hbf);
    k_kproj<<<dim3(512, 4), 256, 0, stream>>>(hbf, wk, bk, kf, ksum);
    k_kv<<<dim3(16, 16), 256, 0, stream>>>(kf, hbf, Aout);
    k_final<<<16, 256, 0, stream>>>(x, w_in, b_in, wq, bq, wv, bv, wo, bo,
                                    g1, b1, wff1, bff1, wff2, bff2, g2, b2,
                                    gf, bf, wfc, bfc, Aout, ksum, (float*)d_out);
}

// Round 2
// 389.426 us; speedup vs baseline: 2.8956x; 2.8956x over previous
//
#include <hip/hip_runtime.h>
#include <hip/hip_bf16.h>

typedef unsigned short u16;
typedef __attribute__((ext_vector_type(8))) unsigned short ushort8;
typedef __attribute__((ext_vector_type(8))) __bf16 bf16x8;
typedef __attribute__((ext_vector_type(4))) float f32x4;

// N=16, L=4096, IN_DIM=32, D=E=512
#define NB 16
#define SEQ 4096
#define DIM 512
#define INDIM 32
#define NTOK (NB * SEQ)   // 65536

static __device__ __forceinline__ u16 f2bf(float f) {
    union { float f; unsigned u; } x; x.f = f;
    unsigned r = (x.u + 0x7FFFu + ((x.u >> 16) & 1u)) >> 16;
    return (u16)r;
}
static __device__ __forceinline__ float bf2f(u16 b) {
    union { unsigned u; float f; } x; x.u = ((unsigned)b) << 16;
    return x.f;
}

// ---------------- Kernel: h = x @ w_in^T + b_in  (store bf16) ----------------
__global__ __launch_bounds__(256) void k_hproj(const float* __restrict__ x,
                                               const float* __restrict__ w_in,
                                               const float* __restrict__ b_in,
                                               u16* __restrict__ hbf) {
    __shared__ float s_w[DIM * INDIM];  // 64 KiB
    __shared__ float s_b[DIM];
    int tid = threadIdx.x;
    const float4* wg = (const float4*)w_in;
    float4* ws4 = (float4*)s_w;
    #pragma unroll
    for (int i = 0; i < 16; ++i) ws4[tid + i * 256] = wg[tid + i * 256];
    if (tid < 128) ((float4*)s_b)[tid] = ((const float4*)b_in)[tid];
    __syncthreads();

    long token = (long)blockIdx.x * 256 + tid;  // 256 blocks -> 65536 tokens
    const float4* xr = (const float4*)(x + token * INDIM);
    float xv[32];
    #pragma unroll
    for (int i = 0; i < 8; ++i) {
        float4 t = xr[i];
        xv[4*i] = t.x; xv[4*i+1] = t.y; xv[4*i+2] = t.z; xv[4*i+3] = t.w;
    }
    for (int d0 = 0; d0 < DIM; d0 += 8) {
        u16 ob[8];
        #pragma unroll
        for (int dd = 0; dd < 8; ++dd) {
            int d = d0 + dd;
            float acc = s_b[d];
            const float* wr = s_w + d * INDIM;
            #pragma unroll
            for (int j = 0; j < 32; ++j) acc += xv[j] * wr[j];
            ob[dd] = f2bf(acc);
        }
        *((ushort8*)(hbf + token * DIM + d0)) = *((ushort8*)ob);
    }
}

// ---------------- Kernel: wk f32 -> bf16 ----------------
__global__ __launch_bounds__(256) void k_cvt(const float* __restrict__ wk,
                                             u16* __restrict__ wkb) {
    long i = ((long)blockIdx.x * 256 + threadIdx.x) * 8;  // 128 blocks covers 262144
    float4 a = *(const float4*)(wk + i);
    float4 b = *(const float4*)(wk + i + 4);
    u16 ob[8] = { f2bf(a.x), f2bf(a.y), f2bf(a.z), f2bf(a.w),
                  f2bf(b.x), f2bf(b.y), f2bf(b.z), f2bf(b.w) };
    *((ushort8*)(wkb + i)) = *((ushort8*)ob);
}

// ---------------- helpers ----------------
__device__ __forceinline__ float dot512(const float* __restrict__ w, const float* v) {
    const float4* a = (const float4*)w;
    const float4* b = (const float4*)v;
    float acc = 0.f;
    #pragma unroll 4
    for (int j = 0; j < 128; ++j) {
        float4 p = a[j], q = b[j];
        acc += p.x * q.x + p.y * q.y + p.z * q.z + p.w * q.w;
    }
    return acc;
}

// ---------------- Kernel: Q0[n] = elu(wq @ h0 + bq)+1 per batch ----------------
__global__ __launch_bounds__(256) void k_q0(const float* __restrict__ x,
                                            const float* __restrict__ w_in,
                                            const float* __restrict__ b_in,
                                            const float* __restrict__ wq,
                                            const float* __restrict__ bq,
                                            float* __restrict__ q0) {
    __shared__ float sx[INDIM];
    __shared__ float sv[DIM];
    int n = blockIdx.x, tid = threadIdx.x;
    if (tid < INDIM) sx[tid] = x[(long)n * SEQ * INDIM + tid];
    __syncthreads();
    for (int d = tid; d < DIM; d += 256) {
        float acc = b_in[d];
        const float* wr = w_in + (long)d * INDIM;
        #pragma unroll
        for (int j = 0; j < INDIM; ++j) acc += sx[j] * wr[j];
        sv[d] = acc;
    }
    __syncthreads();
    for (int e = tid; e < DIM; e += 256) {
        float a = bq[e] + dot512(wq + (long)e * DIM, sv);
        q0[n * DIM + e] = (a > 0.f) ? (a + 1.f) : __expf(a);
    }
}

// ------- Kernel: fused MFMA GEMM kf = elu(h@wk^T+bk)+1 ; w[token] += kf . Q0 -------
// M=65536 (tokens), N=512 (e), K=512. 128x128 tile, BK=32, 4 waves (2x2), 16x16x32 MFMA.
#define BM 128
#define BN 128
#define BK 32
__global__ __launch_bounds__(256) void k_kw(const u16* __restrict__ hbf,
                                            const u16* __restrict__ wkb,
                                            const float* __restrict__ bk,
                                            const float* __restrict__ q0,
                                            float* __restrict__ w) {
    __shared__ u16 sA[BM * BK];  // [m][k], 8 KiB
    __shared__ u16 sB[BN * BK];  // [e][k], 8 KiB
    int tid = threadIdx.x;
    int lane = tid & 63;
    int wid = tid >> 6;          // 0..3
    int wr = wid >> 1, wc = wid & 1;
    int t_base = blockIdx.x * BM;
    int e_base = blockIdx.y * BN;
    int batch = t_base >> 12;

    f32x4 acc[4][4] = {};        // [mi][ni]

    int arow = lane >> 2;            // 0..15
    int akoff = (lane & 3) * 8;      // element offset 0,8,16,24
    int frow = lane & 15;
    int fk = (lane >> 4) * 8;

    for (int k0 = 0; k0 < DIM; k0 += BK) {
        // stage A (h tile) and B (wk tile) via async global->LDS, 16B/lane
        #pragma unroll
        for (int iss = 0; iss < 2; ++iss) {
            int r = wid * 32 + iss * 16 + arow;
            const u16* g = hbf + (long)(t_base + r) * DIM + k0 + akoff;
            u16* l = sA + (wid * 32 + iss * 16) * BK;
            __builtin_amdgcn_global_load_lds(
                (const __attribute__((address_space(1))) void*)g,
                (__attribute__((address_space(3))) void*)l, 16, 0, 0);
        }
        #pragma unroll
        for (int iss = 0; iss < 2; ++iss) {
            int r = wid * 32 + iss * 16 + arow;
            const u16* g = wkb + (long)(e_base + r) * DIM + k0 + akoff;
            u16* l = sB + (wid * 32 + iss * 16) * BK;
            __builtin_amdgcn_global_load_lds(
                (const __attribute__((address_space(1))) void*)g,
                (__attribute__((address_space(3))) void*)l, 16, 0, 0);
        }
        __syncthreads();

        bf16x8 fa[4], fb[4];
        #pragma unroll
        for (int mi = 0; mi < 4; ++mi)
            fa[mi] = *reinterpret_cast<const bf16x8*>(&sA[(wr * 64 + mi * 16 + frow) * BK + fk]);
        #pragma unroll
        for (int ni = 0; ni < 4; ++ni)
            fb[ni] = *reinterpret_cast<const bf16x8*>(&sB[(wc * 64 + ni * 16 + frow) * BK + fk]);
        #pragma unroll
        for (int mi = 0; mi < 4; ++mi)
            #pragma unroll
            for (int ni = 0; ni < 4; ++ni)
                acc[mi][ni] = __builtin_amdgcn_mfma_f32_16x16x32_bf16(fa[mi], fb[ni], acc[mi][ni], 0, 0, 0);
        __syncthreads();
    }

    // epilogue: bias + elu+1, dot with Q0 along e, reduce over 16 cols, atomic to w
    int col = lane & 15;
    int rgrp = lane >> 4;  // 0..3
    float qv[4], bkv[4];
    #pragma unroll
    for (int ni = 0; ni < 4; ++ni) {
        int e = e_base + wc * 64 + ni * 16 + col;
        qv[ni] = q0[batch * DIM + e];
        bkv[ni] = bk[e];
    }
    #pragma unroll
    for (int mi = 0; mi < 4; ++mi) {
        #pragma unroll
        for (int reg = 0; reg < 4; ++reg) {
            float s = 0.f;
            #pragma unroll
            for (int ni = 0; ni < 4; ++ni) {
                float v = acc[mi][ni][reg] + bkv[ni];
                v = (v > 0.f) ? (v + 1.f) : __expf(v);  // elu+1
                s += v * qv[ni];
            }
            #pragma unroll
            for (int off = 1; off < 16; off <<= 1)
                s += __shfl_xor(s, off, 64);
            if (col == 0) {
                int row = t_base + wr * 64 + mi * 16 + rgrp * 4 + reg;
                atomicAdd(&w[row], s);
            }
        }
    }
}

// ------- Kernel: u[n] = sum_s w_s * h_s ; zdot[n] = sum_s w_s -------
__global__ __launch_bounds__(256) void k_u(const u16* __restrict__ hbf,
                                           const float* __restrict__ w,
                                           float* __restrict__ u,
                                           float* __restrict__ zdot) {
    __shared__ float sw[128];
    __shared__ float su[4][512];
    int tid = threadIdx.x;
    int chunk = blockIdx.x;          // 512 chunks of 128 tokens
    int batch = chunk >> 5;
    long s0 = (long)chunk * 128;
    if (tid < 128) sw[tid] = w[s0 + tid];
    __syncthreads();

    // zdot partial
    {
        float z = (tid < 128) ? sw[tid] : 0.f;
        #pragma unroll
        for (int off = 32; off > 0; off >>= 1) z += __shfl_xor(z, off, 64);
        if (tid == 0 || tid == 64) atomicAdd(&zdot[batch], z);
    }

    int mg = (tid & 63) * 8;
    int rg = tid >> 6;
    float ua[8] = {};
    for (int r = rg; r < 128; r += 4) {
        float wsv = sw[r];
        ushort8 hv = *(const ushort8*)(hbf + (s0 + r) * DIM + mg);
        #pragma unroll
        for (int j = 0; j < 8; ++j) ua[j] += wsv * bf2f(hv[j]);
    }
    #pragma unroll
    for (int j = 0; j < 8; ++j) su[rg][mg + j] = ua[j];
    __syncthreads();
    if (tid < 128) {
        #pragma unroll
        for (int jj = 0; jj < 4; ++jj) {
            int m = tid * 4 + jj;
            float s = su[0][m] + su[1][m] + su[2][m] + su[3][m];
            atomicAdd(&u[batch * DIM + m], s);
        }
    }
}

// ---------------- Kernel: per-batch finalize (512 threads, one d each) ----------------
__device__ __forceinline__ float bred512(float v, float* sred, int tid) {
    sred[tid] = v;
    __syncthreads();
    #pragma unroll
    for (int s = 256; s > 0; s >>= 1) {
        if (tid < s) sred[tid] += sred[tid + s];
        __syncthreads();
    }
    float r = sred[0];
    __syncthreads();
    return r;
}

__global__ __launch_bounds__(512) void k_final(
    const float* __restrict__ x, const float* __restrict__ w_in, const float* __restrict__ b_in,
    const float* __restrict__ wv, const float* __restrict__ bv,
    const float* __restrict__ wo, const float* __restrict__ bo,
    const float* __restrict__ g1, const float* __restrict__ b1,
    const float* __restrict__ wff1, const float* __restrict__ bff1,
    const float* __restrict__ wff2, const float* __restrict__ bff2,
    const float* __restrict__ g2, const float* __restrict__ b2,
    const float* __restrict__ gf, const float* __restrict__ bfv,
    const float* __restrict__ wfc, const float* __restrict__ bfc,
    const float* __restrict__ u_in, const float* __restrict__ zdot,
    float* __restrict__ out) {
    __shared__ float sx[INDIM];
    __shared__ float su[DIM];   // u
    __shared__ float sf[DIM];   // attn / ff hidden
    __shared__ float sr1[DIM];  // LN1 out
    __shared__ float sred[512];

    int n = blockIdx.x, tid = threadIdx.x;  // tid = d, 0..511
    if (tid < INDIM) sx[tid] = x[(long)n * SEQ * INDIM + tid];
    su[tid] = u_in[n * DIM + tid];
    __syncthreads();

    // h0
    float h0;
    {
        float acc = b_in[tid];
        const float4* wr = (const float4*)(w_in + (long)tid * INDIM);
        #pragma unroll
        for (int j = 0; j < 8; ++j) {
            float4 p = wr[j];
            acc += p.x * sx[4*j] + p.y * sx[4*j+1] + p.z * sx[4*j+2] + p.w * sx[4*j+3];
        }
        h0 = acc;
    }

    float zd = zdot[n];
    float Z = 1.f / (zd + 1e-6f);

    // attn = Z*(wv@u) + zdot*Z*bv
    sf[tid] = Z * dot512(wv + (long)tid * DIM, su) + zd * Z * bv[tid];
    __syncthreads();

    // o = wo@attn + bo ; r = h0 + o ; LN1
    float r = h0 + bo[tid] + dot512(wo + (long)tid * DIM, sf);
    {
        float mu = bred512(r, sred, tid) * (1.f / DIM);
        float ms = bred512(r * r, sred, tid) * (1.f / DIM);
        float inv = rsqrtf(ms - mu * mu + 1e-5f);
        sr1[tid] = (r - mu) * inv * g1[tid] + b1[tid];
    }
    __syncthreads();

    // FF
    {
        float f = bff1[tid] + dot512(wff1 + (long)tid * DIM, sr1);
        sf[tid] = f > 0.f ? f : 0.f;
    }
    __syncthreads();
    float y = sr1[tid] + bff2[tid] + dot512(wff2 + (long)tid * DIM, sf);

    // LN2
    float h2;
    {
        float mu = bred512(y, sred, tid) * (1.f / DIM);
        float ms = bred512(y * y, sred, tid) * (1.f / DIM);
        float inv = rsqrtf(ms - mu * mu + 1e-5f);
        h2 = (y - mu) * inv * g2[tid] + b2[tid];
    }
    // LN final
    float h3;
    {
        float mu = bred512(h2, sred, tid) * (1.f / DIM);
        float ms = bred512(h2 * h2, sred, tid) * (1.f / DIM);
        float inv = rsqrtf(ms - mu * mu + 1e-5f);
        h3 = (h2 - mu) * inv * gf[tid] + bfv[tid];
    }
    // out
    {
        float p = wfc[tid] * h3;
        float tot = bred512(p, sred, tid);
        if (tid == 0) out[n] = tot + bfc[0];
    }
}

extern "C" void kernel_launch(void* const* d_in, const int* in_sizes, int n_in,
                              void* d_out, int out_size, void* d_ws, size_t ws_size,
                              hipStream_t stream) {
    const float* x    = (const float*)d_in[0];
    const float* w_in = (const float*)d_in[1];
    const float* b_in = (const float*)d_in[2];
    const float* wq   = (const float*)d_in[3];
    const float* bq   = (const float*)d_in[4];
    const float* wk   = (const float*)d_in[5];
    const float* bk   = (const float*)d_in[6];
    const float* wv   = (const float*)d_in[7];
    const float* bv   = (const float*)d_in[8];
    const float* wo   = (const float*)d_in[9];
    const float* bo   = (const float*)d_in[10];
    const float* g1   = (const float*)d_in[11];
    const float* b1   = (const float*)d_in[12];
    const float* wff1 = (const float*)d_in[13];
    const float* bff1 = (const float*)d_in[14];
    const float* wff2 = (const float*)d_in[15];
    const float* bff2 = (const float*)d_in[16];
    const float* g2   = (const float*)d_in[17];
    const float* b2   = (const float*)d_in[18];
    const float* gf   = (const float*)d_in[19];
    const float* bf   = (const float*)d_in[20];
    const float* wfc  = (const float*)d_in[21];
    const float* bfc  = (const float*)d_in[22];

    char* ws = (char*)d_ws;
    u16*   hbf  = (u16*)ws;                          // 64 MiB : h bf16 [65536][512]
    u16*   wkb  = (u16*)(ws + 67108864);             // 512 KiB: wk bf16 [512][512]
    float* q0   = (float*)(ws + 67108864 + 524288);  // 32 KiB : Q0 f32 [16][512]
    float* wtok = (float*)(ws + 67108864 + 557056);  // 256 KiB: w f32 [65536]
    float* u    = (float*)(ws + 67108864 + 819200);  // 32 KiB : u f32 [16][512]
    float* zd   = (float*)(ws + 67108864 + 851968);  // 64 B   : zdot f32 [16]

    hipMemsetAsync(wtok, 0, NTOK * sizeof(float), stream);
    hipMemsetAsync(u, 0, NB * DIM * sizeof(float), stream);
    hipMemsetAsync(zd, 0, NB * sizeof(float), stream);

    k_cvt<<<128, 256, 0, stream>>>(wk, wkb);
    k_hproj<<<256, 256, 0, stream>>>(x, w_in, b_in, hbf);
    k_q0<<<NB, 256, 0, stream>>>(x, w_in, b_in, wq, bq, q0);
    k_kw<<<dim3(NTOK / BM, DIM / BN), 256, 0, stream>>>(hbf, wkb, bk, q0, wtok);
    k_u<<<512, 256, 0, stream>>>(hbf, wtok, u, zd);
    k_final<<<NB, 512, 0, stream>>>(x, w_in, b_in, wv, bv, wo, bo,
                                    g1, b1, wff1, bff1, wff2, bff2, g2, b2,
                                    gf, bf, wfc, bfc, u, zd, (float*)d_out);
}

// Round 3
// 191.641 us; speedup vs baseline: 5.8841x; 2.0321x over previous
//
#include <hip/hip_runtime.h>
#include <hip/hip_bf16.h>

typedef unsigned short u16;
typedef __attribute__((ext_vector_type(8))) unsigned short ushort8;
typedef __attribute__((ext_vector_type(8))) __bf16 bf16x8;
typedef __attribute__((ext_vector_type(4))) float f32x4;

// N=16, L=4096, IN_DIM=32, D=E=512
#define NB 16
#define SEQ 4096
#define DIM 512
#define INDIM 32
#define NTOK (NB * SEQ)   // 65536

static __device__ __forceinline__ u16 f2bf(float f) {
    union { float f; unsigned u; } x; x.f = f;
    unsigned r = (x.u + 0x7FFFu + ((x.u >> 16) & 1u)) >> 16;
    return (u16)r;
}

// ---------- Kernel: wk2 = wk @ w_in (512x32 bf16), bk2 = bk + wk @ b_in ----------
__global__ __launch_bounds__(256) void k_prep(const float* __restrict__ wk,
                                              const float* __restrict__ w_in,
                                              const float* __restrict__ b_in,
                                              const float* __restrict__ bk,
                                              u16* __restrict__ wk2b,
                                              float* __restrict__ bk2) {
    int t = blockIdx.x * 256 + threadIdx.x;   // 64 blocks -> 16384 threads
    int e = t >> 5, j = t & 31;
    const float* wkr = wk + (long)e * DIM;
    float acc = 0.f, accb = 0.f;
    for (int d = 0; d < DIM; d += 4) {
        float4 wv = *(const float4*)(wkr + d);
        acc += wv.x * w_in[(d + 0) * INDIM + j];
        acc += wv.y * w_in[(d + 1) * INDIM + j];
        acc += wv.z * w_in[(d + 2) * INDIM + j];
        acc += wv.w * w_in[(d + 3) * INDIM + j];
        accb += wv.x * b_in[d + 0] + wv.y * b_in[d + 1]
              + wv.z * b_in[d + 2] + wv.w * b_in[d + 3];
    }
    wk2b[e * INDIM + j] = f2bf(acc);
    if (j == 0) bk2[e] = bk[e] + accb;
}

// ---------- Kernel: Q0[n] = elu(wq @ h0 + bq)+1, split over 8 e-slices ----------
__global__ __launch_bounds__(256) void k_q0(const float* __restrict__ x,
                                            const float* __restrict__ w_in,
                                            const float* __restrict__ b_in,
                                            const float* __restrict__ wq,
                                            const float* __restrict__ bq,
                                            float* __restrict__ q0) {
    __shared__ float sx[INDIM];
    __shared__ float sh[DIM];
    __shared__ float sred[64][4];
    int n = blockIdx.x, eb = blockIdx.y * 64;
    int tid = threadIdx.x;
    if (tid < INDIM) sx[tid] = x[(long)n * SEQ * INDIM + tid];
    __syncthreads();
    for (int d = tid; d < DIM; d += 256) {
        float acc = b_in[d];
        const float* wr = w_in + (long)d * INDIM;
        #pragma unroll
        for (int j = 0; j < INDIM; ++j) acc += sx[j] * wr[j];
        sh[d] = acc;
    }
    __syncthreads();
    int e = eb + (tid >> 2), dq = (tid & 3) * 128;
    float p = 0.f;
    const float* wr = wq + (long)e * DIM + dq;
    for (int d = 0; d < 128; d += 4) {
        float4 v = *(const float4*)(wr + d);
        p += v.x * sh[dq + d] + v.y * sh[dq + d + 1]
           + v.z * sh[dq + d + 2] + v.w * sh[dq + d + 3];
    }
    sred[tid >> 2][tid & 3] = p;
    __syncthreads();
    if (tid < 64) {
        float a = bq[eb + tid] + sred[tid][0] + sred[tid][1] + sred[tid][2] + sred[tid][3];
        q0[n * DIM + eb + tid] = (a > 0.f) ? (a + 1.f) : __expf(a);
    }
}

// ---------- Kernel: w_s = sum_e (elu(x_s.wk2_e + bk2_e)+1) q0_e ; fold xu, zdot ----------
// MFMA 16x16x32, M=65536 tokens, N=512 (all e per block), K=32. BM=128, 4 waves.
#define WBM 128
__global__ __launch_bounds__(256) void k_w(const float* __restrict__ x,
                                           const u16* __restrict__ wk2b,
                                           const float* __restrict__ bk2,
                                           const float* __restrict__ q0,
                                           float* __restrict__ xu,
                                           float* __restrict__ zd) {
    __shared__ u16 sB[DIM * 40];     // 40 KiB, row stride 40 u16 (pad 8) for bank spread
    __shared__ float sw[WBM];
    __shared__ float sxu[8][32];
    __shared__ float szz[8];
    int tid = threadIdx.x;
    int lane = tid & 63, wid = tid >> 6;
    long tbase = (long)blockIdx.x * WBM;
    int batch = (int)(tbase >> 12);

    // stage wk2b -> LDS (padded)
    #pragma unroll
    for (int p = 0; p < 8; ++p) {
        int f = (p * 256 + tid) * 8;     // element index, covers 512*32
        int row = f >> 5, colc = f & 31;
        ushort8 v = *(const ushort8*)(wk2b + f);
        *(ushort8*)(sB + row * 40 + colc) = v;
    }

    int col = lane & 15;
    int koff = (lane >> 4) * 8;
    // preload q0 / bk2 per-lane vectors (e = ni*16 + col)
    float q0v[32], bkv[32];
    #pragma unroll
    for (int ni = 0; ni < 32; ++ni) {
        q0v[ni] = q0[batch * DIM + ni * 16 + col];
        bkv[ni] = bk2[ni * 16 + col];
    }
    // A fragments direct from global x (f32 -> bf16 on the fly); 2 mi per wave
    bf16x8 fa[2];
    #pragma unroll
    for (int mi = 0; mi < 2; ++mi) {
        const float* xr = x + (tbase + wid * 32 + mi * 16 + col) * INDIM + koff;
        float4 a0 = *(const float4*)(xr);
        float4 a1 = *(const float4*)(xr + 4);
        u16 tmp[8] = { f2bf(a0.x), f2bf(a0.y), f2bf(a0.z), f2bf(a0.w),
                       f2bf(a1.x), f2bf(a1.y), f2bf(a1.z), f2bf(a1.w) };
        fa[mi] = *(bf16x8*)tmp;
    }
    __syncthreads();

    f32x4 zero = {0.f, 0.f, 0.f, 0.f};
    float wpart[2][4] = {};
    #pragma unroll
    for (int nc = 0; nc < 4; ++nc) {
        bf16x8 fb[8];
        #pragma unroll
        for (int nj = 0; nj < 8; ++nj) {
            int row = (nc * 8 + nj) * 16 + col;
            fb[nj] = *(const bf16x8*)(sB + row * 40 + koff);
        }
        #pragma unroll
        for (int mi = 0; mi < 2; ++mi) {
            #pragma unroll
            for (int nj = 0; nj < 8; ++nj) {
                f32x4 acc = __builtin_amdgcn_mfma_f32_16x16x32_bf16(fa[mi], fb[nj], zero, 0, 0, 0);
                int ni = nc * 8 + nj;
                #pragma unroll
                for (int r = 0; r < 4; ++r) {
                    float v = acc[r] + bkv[ni];
                    v = (v > 0.f) ? (v + 1.f) : __expf(v);   // elu+1
                    wpart[mi][r] += v * q0v[ni];
                }
            }
        }
    }
    // reduce across the 16 cols of each C row-group; C row = (lane>>4)*4 + r
    #pragma unroll
    for (int mi = 0; mi < 2; ++mi) {
        #pragma unroll
        for (int r = 0; r < 4; ++r) {
            float s = wpart[mi][r];
            s += __shfl_xor(s, 1, 64); s += __shfl_xor(s, 2, 64);
            s += __shfl_xor(s, 4, 64); s += __shfl_xor(s, 8, 64);
            if (col == 0) sw[wid * 32 + mi * 16 + (lane >> 4) * 4 + r] = s;
        }
    }
    __syncthreads();
    // fold: xu[batch][j] += sum_s w_s x_s[j] ; zdot[batch] += sum_s w_s
    {
        int j = tid & 31, g = tid >> 5;   // 8 token-groups
        float a = 0.f, z = 0.f;
        for (int tl = g; tl < WBM; tl += 8) {
            float wv = sw[tl];
            a += wv * x[(tbase + tl) * INDIM + j];
            if (j == 0) z += wv;
        }
        sxu[g][j] = a;
        if (j == 0) szz[g] = z;
    }
    __syncthreads();
    if (tid < 32) {
        float a = 0.f;
        #pragma unroll
        for (int g = 0; g < 8; ++g) a += sxu[g][tid];
        atomicAdd(&xu[batch * INDIM + tid], a);
    } else if (tid == 32) {
        float z = 0.f;
        #pragma unroll
        for (int g = 0; g < 8; ++g) z += szz[g];
        atomicAdd(&zd[batch], z);
    }
}

// ---------------- helpers ----------------
__device__ __forceinline__ float dot512(const float* __restrict__ w, const float* v) {
    const float4* a = (const float4*)w;
    const float4* b = (const float4*)v;
    float acc = 0.f;
    #pragma unroll 4
    for (int j = 0; j < 128; ++j) {
        float4 p = a[j], q = b[j];
        acc += p.x * q.x + p.y * q.y + p.z * q.z + p.w * q.w;
    }
    return acc;
}

__device__ __forceinline__ float bred512(float v, float* sred, int tid) {
    sred[tid] = v;
    __syncthreads();
    #pragma unroll
    for (int s = 256; s > 0; s >>= 1) {
        if (tid < s) sred[tid] += sred[tid + s];
        __syncthreads();
    }
    float r = sred[0];
    __syncthreads();
    return r;
}

// ---------------- Kernel: per-batch finalize ----------------
__global__ __launch_bounds__(512) void k_final(
    const float* __restrict__ x, const float* __restrict__ w_in, const float* __restrict__ b_in,
    const float* __restrict__ wv, const float* __restrict__ bv,
    const float* __restrict__ wo, const float* __restrict__ bo,
    const float* __restrict__ g1, const float* __restrict__ b1,
    const float* __restrict__ wff1, const float* __restrict__ bff1,
    const float* __restrict__ wff2, const float* __restrict__ bff2,
    const float* __restrict__ g2, const float* __restrict__ b2,
    const float* __restrict__ gf, const float* __restrict__ bfv,
    const float* __restrict__ wfc, const float* __restrict__ bfc,
    const float* __restrict__ xu, const float* __restrict__ zd,
    float* __restrict__ out) {
    __shared__ float sx[INDIM];
    __shared__ float sxu[INDIM];
    __shared__ float su[DIM];   // u
    __shared__ float sf[DIM];   // attn / ff hidden
    __shared__ float sr1[DIM];  // LN1 out
    __shared__ float sred[512];

    int n = blockIdx.x, tid = threadIdx.x;  // tid = d, 0..511
    if (tid < INDIM) {
        sx[tid] = x[(long)n * SEQ * INDIM + tid];
        sxu[tid] = xu[n * INDIM + tid];
    }
    __syncthreads();

    float zdn = zd[n];
    float Z = 1.f / (zdn + 1e-6f);

    // h0 and u = w_in @ xu + zdot*b_in (same weight rows, fused)
    float h0;
    {
        float acc = b_in[tid];
        float uacc = zdn * b_in[tid];
        const float* wr = w_in + (long)tid * INDIM;
        #pragma unroll
        for (int j = 0; j < INDIM; ++j) {
            float wv_ = wr[j];
            acc += wv_ * sx[j];
            uacc += wv_ * sxu[j];
        }
        h0 = acc;
        su[tid] = uacc;
    }
    __syncthreads();

    // attn = Z*(wv@u) + zdot*Z*bv
    sf[tid] = Z * dot512(wv + (long)tid * DIM, su) + zdn * Z * bv[tid];
    __syncthreads();

    // o = wo@attn + bo ; r = h0 + o ; LN1
    float r = h0 + bo[tid] + dot512(wo + (long)tid * DIM, sf);
    {
        float mu = bred512(r, sred, tid) * (1.f / DIM);
        float ms = bred512(r * r, sred, tid) * (1.f / DIM);
        float inv = rsqrtf(ms - mu * mu + 1e-5f);
        sr1[tid] = (r - mu) * inv * g1[tid] + b1[tid];
    }
    __syncthreads();

    // FF
    {
        float f = bff1[tid] + dot512(wff1 + (long)tid * DIM, sr1);
        sf[tid] = f > 0.f ? f : 0.f;
    }
    __syncthreads();
    float y = sr1[tid] + bff2[tid] + dot512(wff2 + (long)tid * DIM, sf);

    // LN2
    float h2;
    {
        float mu = bred512(y, sred, tid) * (1.f / DIM);
        float ms = bred512(y * y, sred, tid) * (1.f / DIM);
        float inv = rsqrtf(ms - mu * mu + 1e-5f);
        h2 = (y - mu) * inv * g2[tid] + b2[tid];
    }
    // LN final
    float h3;
    {
        float mu = bred512(h2, sred, tid) * (1.f / DIM);
        float ms = bred512(h2 * h2, sred, tid) * (1.f / DIM);
        float inv = rsqrtf(ms - mu * mu + 1e-5f);
        h3 = (h2 - mu) * inv * gf[tid] + bfv[tid];
    }
    // out
    {
        float p = wfc[tid] * h3;
        float tot = bred512(p, sred, tid);
        if (tid == 0) out[n] = tot + bfc[0];
    }
}

extern "C" void kernel_launch(void* const* d_in, const int* in_sizes, int n_in,
                              void* d_out, int out_size, void* d_ws, size_t ws_size,
                              hipStream_t stream) {
    const float* x    = (const float*)d_in[0];
    const float* w_in = (const float*)d_in[1];
    const float* b_in = (const float*)d_in[2];
    const float* wq   = (const float*)d_in[3];
    const float* bq   = (const float*)d_in[4];
    const float* wk   = (const float*)d_in[5];
    const float* bk   = (const float*)d_in[6];
    const float* wv   = (const float*)d_in[7];
    const float* bv   = (const float*)d_in[8];
    const float* wo   = (const float*)d_in[9];
    const float* bo   = (const float*)d_in[10];
    const float* g1   = (const float*)d_in[11];
    const float* b1   = (const float*)d_in[12];
    const float* wff1 = (const float*)d_in[13];
    const float* bff1 = (const float*)d_in[14];
    const float* wff2 = (const float*)d_in[15];
    const float* bff2 = (const float*)d_in[16];
    const float* g2   = (const float*)d_in[17];
    const float* b2   = (const float*)d_in[18];
    const float* gf   = (const float*)d_in[19];
    const float* bf   = (const float*)d_in[20];
    const float* wfc  = (const float*)d_in[21];
    const float* bfc  = (const float*)d_in[22];

    char* ws = (char*)d_ws;
    u16*   wk2b = (u16*)ws;                    // 32 KiB : wk2 bf16 [512][32]
    float* bk2  = (float*)(ws + 32768);        // 2 KiB  : bk2 f32 [512]
    float* q0   = (float*)(ws + 32768 + 2048); // 32 KiB : Q0 f32 [16][512]
    float* xu   = (float*)(ws + 67584);        // 2 KiB  : xu f32 [16][32]
    float* zd   = (float*)(ws + 69632);        // 64 B   : zdot f32 [16]

    hipMemsetAsync(xu, 0, NB * INDIM * sizeof(float), stream);
    hipMemsetAsync(zd, 0, NB * sizeof(float), stream);

    k_prep<<<64, 256, 0, stream>>>(wk, w_in, b_in, bk, wk2b, bk2);
    k_q0<<<dim3(NB, 8), 256, 0, stream>>>(x, w_in, b_in, wq, bq, q0);
    k_w<<<NTOK / WBM, 256, 0, stream>>>(x, wk2b, bk2, q0, xu, zd);
    k_final<<<NB, 512, 0, stream>>>(x, w_in, b_in, wv, bv, wo, bo,
                                    g1, b1, wff1, bff1, wff2, bff2, g2, b2,
                                    gf, bf, wfc, bfc, xu, zd, (float*)d_out);
}

// Round 4
// 93.091 us; speedup vs baseline: 12.1132x; 2.0586x over previous
//
#include <hip/hip_runtime.h>
#include <hip/hip_bf16.h>

typedef unsigned short u16;
typedef __attribute__((ext_vector_type(8))) unsigned short ushort8;
typedef __attribute__((ext_vector_type(8))) __bf16 bf16x8;
typedef __attribute__((ext_vector_type(4))) float f32x4;

// N=16, L=4096, IN_DIM=32, D=E=512
#define NB 16
#define SEQ 4096
#define DIM 512
#define INDIM 32
#define NTOK (NB * SEQ)   // 65536

static __device__ __forceinline__ u16 f2bf(float f) {
    union { float f; unsigned u; } x; x.f = f;
    unsigned r = (x.u + 0x7FFFu + ((x.u >> 16) & 1u)) >> 16;
    return (u16)r;
}

__device__ __forceinline__ float dot32(const float* __restrict__ w, const float* v) {
    const float4* a = (const float4*)w;
    float acc = 0.f;
    #pragma unroll
    for (int i = 0; i < 8; ++i) {
        float4 p = a[i];
        acc += p.x * v[4*i] + p.y * v[4*i+1] + p.z * v[4*i+2] + p.w * v[4*i+3];
    }
    return acc;
}

// ===== prepA: wq2=wq@w_in, wk2=wk@w_in(bf16), wv2=wv@w_in; bq2=bq+wq@b_in etc =====
// grid 1536 blocks: mat = bid>>9 (0=wq,1=wk,2=wv), e = bid&511. 256 thr = 8 kc x 32 j.
__global__ __launch_bounds__(256) void k_prepA(const float* __restrict__ wq,
                                               const float* __restrict__ wk,
                                               const float* __restrict__ wv,
                                               const float* __restrict__ w_in,
                                               const float* __restrict__ b_in,
                                               const float* __restrict__ bq,
                                               const float* __restrict__ bk,
                                               float* __restrict__ wq2, float* __restrict__ bq2,
                                               u16* __restrict__ wk2b, float* __restrict__ bk2,
                                               float* __restrict__ wv2, float* __restrict__ bv2) {
    int bid = blockIdx.x;
    int mat = bid >> 9;
    int e = bid & 511;
    int tid = threadIdx.x;
    int kc = tid >> 5, j = tid & 31;
    const float* A = (mat == 0 ? wq : (mat == 1 ? wk : wv)) + (long)e * DIM;
    float acc = 0.f, accb = 0.f;
    int d0 = kc * 64;
    #pragma unroll 8
    for (int i = 0; i < 64; ++i) {
        float a = A[d0 + i];
        acc += a * w_in[(d0 + i) * INDIM + j];
        accb += a * b_in[d0 + i];
    }
    __shared__ float sA[8][32];
    __shared__ float sB[8];
    sA[kc][j] = acc;
    if (j == 0) sB[kc] = accb;
    __syncthreads();
    if (tid < 32) {
        float s = 0.f;
        #pragma unroll
        for (int i = 0; i < 8; ++i) s += sA[i][tid];
        if (mat == 0) wq2[e * INDIM + tid] = s;
        else if (mat == 1) wk2b[e * INDIM + tid] = f2bf(s);
        else wv2[e * INDIM + tid] = s;
    } else if (tid == 32) {
        float s = 0.f;
        #pragma unroll
        for (int i = 0; i < 8; ++i) s += sB[i];
        if (mat == 0) bq2[e] = bq[e] + s;
        else if (mat == 1) bk2[e] = bk[e] + s;
        else bv2[e] = s;
    }
}

// ===== prepB: wo2=wo@wv2, wob=wo@(bv2+bv), bb=b_in+bo ; q0 ; wff2->bf16 =====
// grid 672: [0,512)=wo2 rows, [512,544)=q0, [544,672)=cvt
__global__ __launch_bounds__(256) void k_prepB(const float* __restrict__ wo,
                                               const float* __restrict__ wv2,
                                               const float* __restrict__ bv2,
                                               const float* __restrict__ bv,
                                               const float* __restrict__ b_in,
                                               const float* __restrict__ bo,
                                               const float* __restrict__ wq2,
                                               const float* __restrict__ bq2,
                                               const float* __restrict__ x,
                                               const float* __restrict__ wff2,
                                               float* __restrict__ wo2, float* __restrict__ wob,
                                               float* __restrict__ bb,
                                               float* __restrict__ q0, u16* __restrict__ wff2b) {
    int bid = blockIdx.x;
    int tid = threadIdx.x;
    if (bid < 512) {
        int e = bid;
        int kc = tid >> 5, j = tid & 31;
        const float* A = wo + (long)e * DIM;
        float acc = 0.f, accb = 0.f;
        int d0 = kc * 64;
        #pragma unroll 8
        for (int i = 0; i < 64; ++i) {
            int d = d0 + i;
            float a = A[d];
            acc += a * wv2[d * INDIM + j];
            accb += a * (bv2[d] + bv[d]);
        }
        __shared__ float sA[8][32];
        __shared__ float sB[8];
        sA[kc][j] = acc;
        if (j == 0) sB[kc] = accb;
        __syncthreads();
        if (tid < 32) {
            float s = 0.f;
            #pragma unroll
            for (int i = 0; i < 8; ++i) s += sA[i][tid];
            wo2[e * INDIM + tid] = s;
        } else if (tid == 32) {
            float s = 0.f;
            #pragma unroll
            for (int i = 0; i < 8; ++i) s += sB[i];
            wob[e] = s;
        } else if (tid == 33) {
            bb[e] = b_in[e] + bo[e];
        }
    } else if (bid < 544) {
        __shared__ float sx0[INDIM];
        int n = (bid - 512) >> 1;
        if (tid < INDIM) sx0[tid] = x[(long)n * SEQ * INDIM + tid];
        __syncthreads();
        int e = ((bid - 512) & 1) * 256 + tid;
        float acc = bq2[e] + dot32(wq2 + e * INDIM, sx0);
        q0[n * DIM + e] = (acc > 0.f) ? (acc + 1.f) : __expf(acc);
    } else {
        long i = ((long)(bid - 544) * 256 + tid) * 8;
        float4 a = *(const float4*)(wff2 + i);
        float4 b = *(const float4*)(wff2 + i + 4);
        u16 ob[8] = { f2bf(a.x), f2bf(a.y), f2bf(a.z), f2bf(a.w),
                      f2bf(b.x), f2bf(b.y), f2bf(b.z), f2bf(b.w) };
        *((ushort8*)(wff2b + i)) = *((ushort8*)ob);
    }
}

// ===== prepC: wf1x=wff1.G1.w_in, wf1u=wff1.G1.wo2 ; wf1w,wg1,wf1c,wb1 =====
// grid 1024: type = bid>>9, e = bid&511
__global__ __launch_bounds__(256) void k_prepC(const float* __restrict__ wff1,
                                               const float* __restrict__ w_in,
                                               const float* __restrict__ wo2,
                                               const float* __restrict__ g1,
                                               const float* __restrict__ b1,
                                               const float* __restrict__ wob,
                                               const float* __restrict__ bb,
                                               float* __restrict__ wf1x, float* __restrict__ wf1u,
                                               float* __restrict__ wf1w, float* __restrict__ wf1c,
                                               float* __restrict__ wg1, float* __restrict__ wb1) {
    int bid = blockIdx.x;
    int type = bid >> 9;
    int e = bid & 511;
    int tid = threadIdx.x;
    int kc = tid >> 5, j = tid & 31;
    const float* A = wff1 + (long)e * DIM;
    const float* B = (type == 0) ? w_in : wo2;
    float acc = 0.f, acc0 = 0.f, acc1 = 0.f;
    int d0 = kc * 64;
    #pragma unroll 4
    for (int i = 0; i < 64; ++i) {
        int d = d0 + i;
        float a = A[d];
        float g = g1[d];
        float ag = a * g;
        acc += ag * B[d * INDIM + j];
        if (type == 0) { acc0 += ag * wob[d]; acc1 += ag; }
        else           { acc0 += ag * bb[d];  acc1 += a * b1[d]; }
    }
    __shared__ float sA[8][32];
    __shared__ float s0[8], s1v[8];
    sA[kc][j] = acc;
    if (j == 0) { s0[kc] = acc0; s1v[kc] = acc1; }
    __syncthreads();
    if (tid < 32) {
        float s = 0.f;
        #pragma unroll
        for (int i = 0; i < 8; ++i) s += sA[i][tid];
        (type == 0 ? wf1x : wf1u)[e * INDIM + tid] = s;
    } else if (tid == 32) {
        float s = 0.f;
        #pragma unroll
        for (int i = 0; i < 8; ++i) s += s0[i];
        (type == 0 ? wf1w : wf1c)[e] = s;
    } else if (tid == 33) {
        float s = 0.f;
        #pragma unroll
        for (int i = 0; i < 8; ++i) s += s1v[i];
        (type == 0 ? wg1 : wb1)[e] = s;
    }
}

// ===== k_w: w_s = Kf_s . Q0 via MFMA over K=32 ; fold xu, zdot (unchanged) =====
#define WBM 128
__global__ __launch_bounds__(256) void k_w(const float* __restrict__ x,
                                           const u16* __restrict__ wk2b,
                                           const float* __restrict__ bk2,
                                           const float* __restrict__ q0,
                                           float* __restrict__ xu,
                                           float* __restrict__ zd) {
    __shared__ u16 sB[DIM * 40];
    __shared__ float sw[WBM];
    __shared__ float sxu[8][32];
    __shared__ float szz[8];
    int tid = threadIdx.x;
    int lane = tid & 63, wid = tid >> 6;
    long tbase = (long)blockIdx.x * WBM;
    int batch = (int)(tbase >> 12);

    #pragma unroll
    for (int p = 0; p < 8; ++p) {
        int f = (p * 256 + tid) * 8;
        int row = f >> 5, colc = f & 31;
        ushort8 v = *(const ushort8*)(wk2b + f);
        *(ushort8*)(sB + row * 40 + colc) = v;
    }

    int col = lane & 15;
    int koff = (lane >> 4) * 8;
    float q0v[32], bkv[32];
    #pragma unroll
    for (int ni = 0; ni < 32; ++ni) {
        q0v[ni] = q0[batch * DIM + ni * 16 + col];
        bkv[ni] = bk2[ni * 16 + col];
    }
    bf16x8 fa[2];
    #pragma unroll
    for (int mi = 0; mi < 2; ++mi) {
        const float* xr = x + (tbase + wid * 32 + mi * 16 + col) * INDIM + koff;
        float4 a0 = *(const float4*)(xr);
        float4 a1 = *(const float4*)(xr + 4);
        u16 tmp[8] = { f2bf(a0.x), f2bf(a0.y), f2bf(a0.z), f2bf(a0.w),
                       f2bf(a1.x), f2bf(a1.y), f2bf(a1.z), f2bf(a1.w) };
        fa[mi] = *(bf16x8*)tmp;
    }
    __syncthreads();

    f32x4 zero = {0.f, 0.f, 0.f, 0.f};
    float wpart[2][4] = {};
    #pragma unroll
    for (int nc = 0; nc < 4; ++nc) {
        bf16x8 fb[8];
        #pragma unroll
        for (int nj = 0; nj < 8; ++nj) {
            int row = (nc * 8 + nj) * 16 + col;
            fb[nj] = *(const bf16x8*)(sB + row * 40 + koff);
        }
        #pragma unroll
        for (int mi = 0; mi < 2; ++mi) {
            #pragma unroll
            for (int nj = 0; nj < 8; ++nj) {
                f32x4 acc = __builtin_amdgcn_mfma_f32_16x16x32_bf16(fa[mi], fb[nj], zero, 0, 0, 0);
                int ni = nc * 8 + nj;
                #pragma unroll
                for (int r = 0; r < 4; ++r) {
                    float v = acc[r] + bkv[ni];
                    v = (v > 0.f) ? (v + 1.f) : __expf(v);
                    wpart[mi][r] += v * q0v[ni];
                }
            }
        }
    }
    #pragma unroll
    for (int mi = 0; mi < 2; ++mi) {
        #pragma unroll
        for (int r = 0; r < 4; ++r) {
            float s = wpart[mi][r];
            s += __shfl_xor(s, 1, 64); s += __shfl_xor(s, 2, 64);
            s += __shfl_xor(s, 4, 64); s += __shfl_xor(s, 8, 64);
            if (col == 0) sw[wid * 32 + mi * 16 + (lane >> 4) * 4 + r] = s;
        }
    }
    __syncthreads();
    {
        int j = tid & 31, g = tid >> 5;
        float a = 0.f, z = 0.f;
        for (int tl = g; tl < WBM; tl += 8) {
            float wv = sw[tl];
            a += wv * x[(tbase + tl) * INDIM + j];
            if (j == 0) z += wv;
        }
        sxu[g][j] = a;
        if (j == 0) szz[g] = z;
    }
    __syncthreads();
    if (tid < 32) {
        float a = 0.f;
        #pragma unroll
        for (int g = 0; g < 8; ++g) a += sxu[g][tid];
        atomicAdd(&xu[batch * INDIM + tid], a);
    } else if (tid == 32) {
        float z = 0.f;
        #pragma unroll
        for (int g = 0; g < 8; ++g) z += szz[g];
        atomicAdd(&zd[batch], z);
    }
}

// ===== k_mid: per batch: r, LN1, r1, fpre, f (all 32-dots) =====
__device__ __forceinline__ void reduce2_512(float a, float b, int tid, float* lds16,
                                            float& oa, float& ob) {
    #pragma unroll
    for (int off = 1; off < 64; off <<= 1) {
        a += __shfl_xor(a, off, 64);
        b += __shfl_xor(b, off, 64);
    }
    int w = tid >> 6;
    if ((tid & 63) == 0) { lds16[w] = a; lds16[8 + w] = b; }
    __syncthreads();
    float ra = 0.f, rb = 0.f;
    #pragma unroll
    for (int i = 0; i < 8; ++i) { ra += lds16[i]; rb += lds16[8 + i]; }
    oa = ra; ob = rb;
    __syncthreads();
}

__global__ __launch_bounds__(512) void k_mid(const float* __restrict__ x,
                                             const float* __restrict__ w_in,
                                             const float* __restrict__ wo2,
                                             const float* __restrict__ wob,
                                             const float* __restrict__ bb,
                                             const float* __restrict__ wf1x,
                                             const float* __restrict__ wf1u,
                                             const float* __restrict__ wf1w,
                                             const float* __restrict__ wf1c,
                                             const float* __restrict__ wg1,
                                             const float* __restrict__ wb1,
                                             const float* __restrict__ g1,
                                             const float* __restrict__ b1,
                                             const float* __restrict__ bff1,
                                             const float* __restrict__ xu,
                                             const float* __restrict__ zdv,
                                             float* __restrict__ r1buf,
                                             u16* __restrict__ fbuf) {
    __shared__ float sx0[INDIM], sxu[INDIM];
    __shared__ float lds16[16];
    int n = blockIdx.x, tid = threadIdx.x;
    if (tid < INDIM) {
        sx0[tid] = x[(long)n * SEQ * INDIM + tid];
        sxu[tid] = xu[n * INDIM + tid];
    }
    __syncthreads();
    float zd = zdv[n];
    float Z = 1.f / (zd + 1e-6f);
    float zz = zd * Z;
    int d = tid;

    float rd = bb[d] + zz * wob[d] + dot32(w_in + d * INDIM, sx0)
             + Z * dot32(wo2 + d * INDIM, sxu);
    float sum, sumsq;
    reduce2_512(rd, rd * rd, tid, lds16, sum, sumsq);
    float mu1 = sum * (1.f / DIM);
    float s1 = rsqrtf(sumsq * (1.f / DIM) - mu1 * mu1 + 1e-5f);
    float r1d = (rd - mu1) * s1 * g1[d] + b1[d];
    r1buf[n * DIM + d] = r1d;

    float G = dot32(wf1x + d * INDIM, sx0) + Z * dot32(wf1u + d * INDIM, sxu)
            + zz * wf1w[d] + wf1c[d];
    float fp = s1 * (G - mu1 * wg1[d]) + wb1[d] + bff1[d];
    fbuf[n * DIM + d] = f2bf(fmaxf(fp, 0.f));
}

// ===== k_y: v = r1 + wff2@f + bff2  (MFMA, M=16 batches) =====
__global__ __launch_bounds__(256) void k_y(const u16* __restrict__ fbuf,
                                           const u16* __restrict__ wff2b,
                                           const float* __restrict__ bff2,
                                           const float* __restrict__ r1buf,
                                           float* __restrict__ vbuf) {
    int tid = threadIdx.x;
    int lane = tid & 63, w = tid >> 6;
    int dbase = blockIdx.x * 64 + w * 16;
    int cl = lane & 15, kh = lane >> 4;
    f32x4 acc = {0.f, 0.f, 0.f, 0.f};
    const u16* arow = fbuf + cl * DIM + kh * 8;
    const u16* brow = wff2b + (long)(dbase + cl) * DIM + kh * 8;
    #pragma unroll
    for (int kc = 0; kc < 16; ++kc) {
        bf16x8 af = *(const bf16x8*)(arow + kc * 32);
        bf16x8 bf_ = *(const bf16x8*)(brow + kc * 32);
        acc = __builtin_amdgcn_mfma_f32_16x16x32_bf16(af, bf_, acc, 0, 0, 0);
    }
    int dcol = dbase + cl;
    float bfv = bff2[dcol];
    #pragma unroll
    for (int r = 0; r < 4; ++r) {
        int n = kh * 4 + r;
        vbuf[n * DIM + dcol] = acc[r] + bfv + r1buf[n * DIM + dcol];
    }
}

// ===== k_tail: LN2, LNf, fc — one wave per batch, shfl-only =====
__global__ __launch_bounds__(1024) void k_tail(const float* __restrict__ vbuf,
                                               const float* __restrict__ g2,
                                               const float* __restrict__ b2,
                                               const float* __restrict__ gf,
                                               const float* __restrict__ bfv,
                                               const float* __restrict__ wfc,
                                               const float* __restrict__ bfc,
                                               float* __restrict__ out) {
    int tid = threadIdx.x;
    int n = tid >> 6, lane = tid & 63;
    int dbase = lane * 8;
    float v[8];
    {
        const float4* vp = (const float4*)(vbuf + n * DIM + dbase);
        float4 a = vp[0], b = vp[1];
        v[0] = a.x; v[1] = a.y; v[2] = a.z; v[3] = a.w;
        v[4] = b.x; v[5] = b.y; v[6] = b.z; v[7] = b.w;
    }
    float s = 0.f, ss = 0.f;
    #pragma unroll
    for (int i = 0; i < 8; ++i) { s += v[i]; ss += v[i] * v[i]; }
    #pragma unroll
    for (int off = 1; off < 64; off <<= 1) {
        s += __shfl_xor(s, off, 64);
        ss += __shfl_xor(ss, off, 64);
    }
    float mu = s * (1.f / DIM);
    float inv = rsqrtf(ss * (1.f / DIM) - mu * mu + 1e-5f);
    float h2[8];
    {
        const float4* gp = (const float4*)(g2 + dbase);
        const float4* bp = (const float4*)(b2 + dbase);
        float4 ga = gp[0], gb = gp[1], ba = bp[0], bb2 = bp[1];
        float gg[8] = { ga.x, ga.y, ga.z, ga.w, gb.x, gb.y, gb.z, gb.w };
        float bbx[8] = { ba.x, ba.y, ba.z, ba.w, bb2.x, bb2.y, bb2.z, bb2.w };
        #pragma unroll
        for (int i = 0; i < 8; ++i) h2[i] = (v[i] - mu) * inv * gg[i] + bbx[i];
    }
    s = 0.f; ss = 0.f;
    #pragma unroll
    for (int i = 0; i < 8; ++i) { s += h2[i]; ss += h2[i] * h2[i]; }
    #pragma unroll
    for (int off = 1; off < 64; off <<= 1) {
        s += __shfl_xor(s, off, 64);
        ss += __shfl_xor(ss, off, 64);
    }
    float mu2 = s * (1.f / DIM);
    float inv2 = rsqrtf(ss * (1.f / DIM) - mu2 * mu2 + 1e-5f);
    float p = 0.f;
    {
        const float4* gp = (const float4*)(gf + dbase);
        const float4* bp = (const float4*)(bfv + dbase);
        const float4* wp = (const float4*)(wfc + dbase);
        float4 ga = gp[0], gb = gp[1], ba = bp[0], bb2 = bp[1], wa = wp[0], wb = wp[1];
        float gg[8] = { ga.x, ga.y, ga.z, ga.w, gb.x, gb.y, gb.z, gb.w };
        float bbx[8] = { ba.x, ba.y, ba.z, ba.w, bb2.x, bb2.y, bb2.z, bb2.w };
        float ww[8] = { wa.x, wa.y, wa.z, wa.w, wb.x, wb.y, wb.z, wb.w };
        #pragma unroll
        for (int i = 0; i < 8; ++i)
            p += ww[i] * ((h2[i] - mu2) * inv2 * gg[i] + bbx[i]);
    }
    #pragma unroll
    for (int off = 1; off < 64; off <<= 1) p += __shfl_xor(p, off, 64);
    if (lane == 0) out[n] = p + bfc[0];
}

extern "C" void kernel_launch(void* const* d_in, const int* in_sizes, int n_in,
                              void* d_out, int out_size, void* d_ws, size_t ws_size,
                              hipStream_t stream) {
    const float* x    = (const float*)d_in[0];
    const float* w_in = (const float*)d_in[1];
    const float* b_in = (const float*)d_in[2];
    const float* wq   = (const float*)d_in[3];
    const float* bq   = (const float*)d_in[4];
    const float* wk   = (const float*)d_in[5];
    const float* bk   = (const float*)d_in[6];
    const float* wv   = (const float*)d_in[7];
    const float* bv   = (const float*)d_in[8];
    const float* wo   = (const float*)d_in[9];
    const float* bo   = (const float*)d_in[10];
    const float* g1   = (const float*)d_in[11];
    const float* b1   = (const float*)d_in[12];
    const float* wff1 = (const float*)d_in[13];
    const float* bff1 = (const float*)d_in[14];
    const float* wff2 = (const float*)d_in[15];
    const float* bff2 = (const float*)d_in[16];
    const float* g2   = (const float*)d_in[17];
    const float* b2   = (const float*)d_in[18];
    const float* gf   = (const float*)d_in[19];
    const float* bf   = (const float*)d_in[20];
    const float* wfc  = (const float*)d_in[21];
    const float* bfc  = (const float*)d_in[22];

    char* ws = (char*)d_ws;
    float* wq2   = (float*)(ws + 0);         // 64 KiB
    float* bq2   = (float*)(ws + 65536);     // 2 KiB
    u16*   wk2b  = (u16*)  (ws + 67584);     // 32 KiB
    float* bk2   = (float*)(ws + 100352);    // 2 KiB
    float* wv2   = (float*)(ws + 102400);    // 64 KiB
    float* bv2   = (float*)(ws + 167936);    // 2 KiB
    float* wo2   = (float*)(ws + 169984);    // 64 KiB
    float* wob   = (float*)(ws + 235520);    // 2 KiB
    float* bb    = (float*)(ws + 237568);    // 2 KiB
    float* wf1x  = (float*)(ws + 239616);    // 64 KiB
    float* wf1u  = (float*)(ws + 305152);    // 64 KiB
    float* wf1w  = (float*)(ws + 370688);    // 2 KiB
    float* wf1c  = (float*)(ws + 372736);    // 2 KiB
    float* wg1   = (float*)(ws + 374784);    // 2 KiB
    float* wb1   = (float*)(ws + 376832);    // 2 KiB
    u16*   wff2b = (u16*)  (ws + 378880);    // 512 KiB
    float* q0    = (float*)(ws + 903168);    // 32 KiB
    float* xu    = (float*)(ws + 935936);    // 2 KiB
    float* zd    = (float*)(ws + 937984);    // 256 B
    u16*   fbuf  = (u16*)  (ws + 938240);    // 16 KiB
    float* r1buf = (float*)(ws + 954624);    // 32 KiB
    float* vbuf  = (float*)(ws + 987392);    // 32 KiB

    hipMemsetAsync(xu, 0, NB * INDIM * sizeof(float), stream);
    hipMemsetAsync(zd, 0, NB * sizeof(float), stream);

    k_prepA<<<1536, 256, 0, stream>>>(wq, wk, wv, w_in, b_in, bq, bk,
                                      wq2, bq2, wk2b, bk2, wv2, bv2);
    k_prepB<<<672, 256, 0, stream>>>(wo, wv2, bv2, bv, b_in, bo, wq2, bq2, x, wff2,
                                     wo2, wob, bb, q0, wff2b);
    k_prepC<<<1024, 256, 0, stream>>>(wff1, w_in, wo2, g1, b1, wob, bb,
                                      wf1x, wf1u, wf1w, wf1c, wg1, wb1);
    k_w<<<NTOK / WBM, 256, 0, stream>>>(x, wk2b, bk2, q0, xu, zd);
    k_mid<<<NB, 512, 0, stream>>>(x, w_in, wo2, wob, bb, wf1x, wf1u, wf1w, wf1c,
                                  wg1, wb1, g1, b1, bff1, xu, zd, r1buf, fbuf);
    k_y<<<8, 256, 0, stream>>>(fbuf, wff2b, bff2, r1buf, vbuf);
    k_tail<<<1, 1024, 0, stream>>>(vbuf, g2, b2, gf, bf, wfc, bfc, (float*)d_out);
}